// Round 5
// baseline (202.171 us; speedup 1.0000x reference)
//
#include <hip/hip_runtime.h>
#include <hip/hip_bf16.h>
#include <stdint.h>

// Problem constants (fixed by the reference)
#define B_DIM   128
#define N_DIM   36
#define C_DIM   1024
#define KNB     16
#define NKER    8
#define OUTD    1024
#define BN_NODES (B_DIM * N_DIM)     // 4608
#define E_EDGES  (BN_NODES * KNB)    // 73728
#define PI_F 3.14159265358979323846f

// R5 = CALIBRATION ROUND: exact R2 configuration (best measured, 121.64 us)
// with gemm_fused launched 5x (idempotent -> identical proj each replay).
// Delta vs 121.6 = 4 x (GEMM + launch gap). Fill jitter is +-3 us; 4x
// amplification gives GEMM to +-0.75 us.
#define TM 48
#define TN 128
#define BK 64
#define KIT (C_DIM / BK)   // 16
#define CLP 136            // epilogue C-tile LDS leading dim
// LDS shorts: A bufs 2*48*64 = 6144, B bufs 2*128*64 = 16384 -> 22528 (45 KB)
#define A_OFF(p) ((p) * TM * BK)                 // 0 / 3072
#define B_OFF(p) (2 * TM * BK + (p) * TN * BK)   // 6144 / 14336

typedef __attribute__((ext_vector_type(8))) short bf16x8;   // 8 bf16 = 4 VGPRs
typedef __attribute__((ext_vector_type(4))) float floatx4;  // MFMA C/D frag

struct alignas(8)  U16x4 { unsigned short x, y, z, w; };
struct alignas(16) U16x8 { unsigned short s[8]; };

__device__ __forceinline__ unsigned short f2bf(float f) {
  union { float f; uint32_t u; } v; v.f = f;
  uint32_t u = v.u;
  return (unsigned short)((u + 0x7fffu + ((u >> 16) & 1u)) >> 16);  // RNE
}
__device__ __forceinline__ float bf2f_lo(uint32_t pair) {
  union { uint32_t u; float f; } v; v.u = pair << 16;
  return v.f;
}
__device__ __forceinline__ float bf2f_hi(uint32_t pair) {
  union { uint32_t u; float f; } v; v.u = pair & 0xffff0000u;
  return v.f;
}

// async global -> LDS, 16B per lane (global_load_lds_dwordx4).
__device__ __forceinline__ void gload16(const void* g, void* l) {
  __builtin_amdgcn_global_load_lds((__attribute__((address_space(1))) void*)(g),
                                   (__attribute__((address_space(3))) void*)(l),
                                   16, 0, 0);
}

// ---------------------------------------------------------------------------
// Kernel 1: cast conv_w fp32->bf16 + precompute normalized edge weights.
// ---------------------------------------------------------------------------
__global__ __launch_bounds__(256)
void castw_ew_kernel(const float* __restrict__ cw,       // [1024*1024]
                     const float* __restrict__ centre,   // [BN][2]
                     const int*   __restrict__ nbr,      // [BN][16]
                     const float* __restrict__ gw,       // [E]
                     const float* __restrict__ mrho,
                     const float* __restrict__ mth,
                     const float* __restrict__ prho,
                     const float* __restrict__ pth,
                     unsigned short* __restrict__ wb,
                     float* __restrict__ ewg)            // [BN][NKER][KNB]
{
  const int NW4 = (C_DIM * OUTD) / 4;       // 262144
  int tid = blockIdx.x * 256 + threadIdx.x;
  if (tid < NW4) {
    float4 v = ((const float4*)cw)[tid];
    U16x4 o = { f2bf(v.x), f2bf(v.y), f2bf(v.z), f2bf(v.w) };
    ((U16x4*)wb)[tid] = o;
  } else {
    int e = tid - NW4;
    if (e < E_EDGES) {
      int n = e >> 4;
      int m = nbr[e];
      float cx = centre[2 * n]     - centre[2 * m];
      float cy = centre[2 * n + 1] - centre[2 * m + 1];
      float rho   = sqrtf(cx * cx + cy * cy);
      float theta = atan2f(cx, cy);      // jnp.arctan2(coord_x, coord_y)
      float wk[NKER];
      float s = 0.f;
#pragma unroll
      for (int k = 0; k < NKER; ++k) {
        float dr = rho - mrho[k];
        float pr = prho[k];
        float w_r = expf(-0.5f * dr * dr / (1e-14f + pr * pr));
        float fa = fabsf(theta - mth[k]);
        float sa = fabsf(2.0f * PI_F - fa);
        float mm = fminf(fa, sa);
        float pt = pth[k];
        float w_t = expf(-0.5f * mm * mm / (1e-14f + pt * pt));
        float ww = w_r * w_t;
        wk[k] = (ww != ww) ? 0.f : ww;   // NaN guard (reference parity)
        s += wk[k];
      }
      float scale = gw[e] / s;
      int j = e & 15;
#pragma unroll
      for (int k = 0; k < NKER; ++k)
        ewg[(size_t)n * (NKER * KNB) + k * KNB + j] = wk[k] * scale;
    }
  }
}

// ---------------------------------------------------------------------------
// Kernel 2: proj = feats(fp32, cast in-kernel) @ conv_w^T(bf16, gload_lds).
// R2 structure: 48x128 tile, 4 waves as 1x4 (48x32 each), dbuf BK=64.
// ---------------------------------------------------------------------------
__global__ __launch_bounds__(256)
void gemm_fused(const float* __restrict__ A,            // [4608][1024] fp32
                const unsigned short* __restrict__ Bt,  // [1024][1024] bf16
                unsigned short* __restrict__ D)         // [4608][1024] bf16
{
  __shared__ unsigned short smem[2 * TM * BK + 2 * TN * BK];  // 45 KB

  const int tid  = threadIdx.x;
  const int lane = tid & 63;
  const int wv   = tid >> 6;        // wave 0..3 -> col group of 32
  const int row0 = blockIdx.x * TM;
  const int col0 = blockIdx.y * TN;

  const int q  = lane >> 4;         // quad
  const int lr = lane & 15;

  floatx4 acc[3][2] = {};

  // ---- B staging map (16B chunks, chunk c -> row c>>3, qcol c&7, XOR) ----
  int offB[4];
#pragma unroll
  for (int i = 0; i < 4; ++i) {
    int c = tid + 256 * i, row = c >> 3, qc = c & 7;
    offB[i] = (col0 + row) * C_DIM + (qc ^ (row & 7)) * 8;
  }

  // ---- A staging map (fp32 source -> bf16 LDS, XOR swizzle) ----
  const int r0A = tid >> 3;                      // rows 0..31
  const int gA0 = (row0 + r0A) * C_DIM + (tid & 7) * 8;
  const int r2A = 32 + (tid >> 4);               // rows 32..47
  const int gA2 = (row0 + r2A) * C_DIM + (tid & 15) * 4;
  const int wA0 = r0A * BK + (((tid & 7) ^ (r0A & 7)) * 8);
  const int wA2 = r2A * BK + ((((tid >> 1) & 7) ^ (r2A & 7)) * 8) + (tid & 1) * 4;

  float4 a0, a1, a2;

#define LOADA(T) do {                                                        \
    a0 = *(const float4*)&A[gA0 + (T) * BK];                                 \
    a1 = *(const float4*)&A[gA0 + 4 + (T) * BK];                             \
    a2 = *(const float4*)&A[gA2 + (T) * BK];                                 \
  } while (0)

#define WRITEA(P) do {                                                       \
    U16x8 w8;                                                                \
    w8.s[0] = f2bf(a0.x); w8.s[1] = f2bf(a0.y);                              \
    w8.s[2] = f2bf(a0.z); w8.s[3] = f2bf(a0.w);                              \
    w8.s[4] = f2bf(a1.x); w8.s[5] = f2bf(a1.y);                              \
    w8.s[6] = f2bf(a1.z); w8.s[7] = f2bf(a1.w);                              \
    *(U16x8*)&smem[A_OFF(P) + wA0] = w8;                                     \
    U16x4 w4 = { f2bf(a2.x), f2bf(a2.y), f2bf(a2.z), f2bf(a2.w) };           \
    *(U16x4*)&smem[A_OFF(P) + wA2] = w4;                                     \
  } while (0)

#define DMAB(T, P) do {                                                      \
    _Pragma("unroll") for (int i = 0; i < 4; ++i)                            \
      gload16(Bt + offB[i] + (T) * BK,                                       \
              &smem[B_OFF(P) + (tid + 256 * i) * 8]);                        \
  } while (0)

  // prologue: tile 0 into buf 0
  LOADA(0);
  DMAB(0, 0);
  WRITEA(0);            // compiler-inserted vmcnt wait for a0..a2
  __syncthreads();      // buf0 (A writes + B DMA) visible

  for (int t = 0; t < KIT; ++t) {
    const int p = t & 1;
    if (t + 1 < KIT) { DMAB(t + 1, 1 - p); LOADA(t + 1); }

    const int aBase = A_OFF(p);
    const int bBase = B_OFF(p);
#pragma unroll
    for (int kc = 0; kc < 2; ++kc) {
      const int sc = ((kc * 4 + q) ^ (lr & 7)) * 8;
      bf16x8 af[3], bfr[2];
#pragma unroll
      for (int i = 0; i < 3; ++i)
        af[i]  = *(const bf16x8*)&smem[aBase + (i * 16 + lr) * BK + sc];
#pragma unroll
      for (int j = 0; j < 2; ++j)
        bfr[j] = *(const bf16x8*)&smem[bBase + (wv * 32 + j * 16 + lr) * BK + sc];
#pragma unroll
      for (int i = 0; i < 3; ++i)
#pragma unroll
        for (int j = 0; j < 2; ++j)
          acc[i][j] = __builtin_amdgcn_mfma_f32_16x16x32_bf16(
              af[i], bfr[j], acc[i][j], 0, 0, 0);
    }

    if (t + 1 < KIT) WRITEA(1 - p);  // vmcnt wait lands AFTER MFMA phase
    __syncthreads();
  }
#undef LOADA
#undef WRITEA
#undef DMAB

  // ---- epilogue: stage C tile (48x128 bf16) in LDS, coalesced stores ----
#pragma unroll
  for (int i = 0; i < 3; ++i)
#pragma unroll
    for (int j = 0; j < 2; ++j)
#pragma unroll
      for (int r = 0; r < 4; ++r)
        smem[(i * 16 + q * 4 + r) * CLP + wv * 32 + j * 16 + lr] =
            f2bf(acc[i][j][r]);
  __syncthreads();
  // full tile = 48 rows x 16 chunks = 768 chunks; thread t does 3
#pragma unroll
  for (int i = 0; i < 3; ++i) {
    int c = tid + 256 * i;
    int row = c >> 4, qc = c & 15;
    *(uint4*)&D[(size_t)(row0 + row) * OUTD + col0 + qc * 8] =
        *(const uint4*)&smem[row * CLP + qc * 8];
  }
}

// ---------------------------------------------------------------------------
// Kernel 3: pure gather-aggregate, channel-sliced + XCD-pinned (unchanged).
// ---------------------------------------------------------------------------
__global__ __launch_bounds__(256)
void agg_gather(const unsigned short* __restrict__ proj,  // [BN][1024] bf16
                const int*   __restrict__ nbr,            // [BN][16]
                const float* __restrict__ ewg,            // [BN][NKER][KNB]
                float* __restrict__ out)                  // [BN][1024] fp32
{
  __shared__ int   idx[8][KNB];
  __shared__ float ewl[8][2][KNB];

  const int bid = blockIdx.x;
  const int x   = bid & 7;                    // XCD (round-robin dispatch)
  const int s   = x >> 1;                     // channel slice 0..3
  const int g   = ((bid >> 3) << 1) | (x & 1);// node group 0..575
  const int n0  = g * 8;
  const int t   = threadIdx.x;

  if (t < 128)
    idx[t >> 4][t & 15] = nbr[(n0 + (t >> 4)) * KNB + (t & 15)];
  {
    int a = t >> 5, r = t & 31;
    ewl[a][r >> 4][r & 15] = ewg[(size_t)(n0 + a) * (NKER * KNB) + s * 32 + r];
  }
  __syncthreads();

  const int a   = t >> 5;
  const int cu  = t & 31;
  const int kk  = cu >> 4;
  const int n   = n0 + a;
  const int ch0 = s * 256 + cu * 8;

  float acc[8] = {0.f, 0.f, 0.f, 0.f, 0.f, 0.f, 0.f, 0.f};
#pragma unroll
  for (int j = 0; j < KNB; ++j) {
    float wvv = ewl[a][kk][j];
    uint4 v = *(const uint4*)&proj[(size_t)idx[a][j] * OUTD + ch0];
    acc[0] += wvv * bf2f_lo(v.x);  acc[1] += wvv * bf2f_hi(v.x);
    acc[2] += wvv * bf2f_lo(v.y);  acc[3] += wvv * bf2f_hi(v.y);
    acc[4] += wvv * bf2f_lo(v.z);  acc[5] += wvv * bf2f_hi(v.z);
    acc[6] += wvv * bf2f_lo(v.w);  acc[7] += wvv * bf2f_hi(v.w);
  }
  float4 r0, r1;
  r0.x = fmaxf(acc[0], 0.f); r0.y = fmaxf(acc[1], 0.f);
  r0.z = fmaxf(acc[2], 0.f); r0.w = fmaxf(acc[3], 0.f);
  r1.x = fmaxf(acc[4], 0.f); r1.y = fmaxf(acc[5], 0.f);
  r1.z = fmaxf(acc[6], 0.f); r1.w = fmaxf(acc[7], 0.f);
  float* o = out + (size_t)n * OUTD + ch0;
  *(float4*)(o)     = r0;
  *(float4*)(o + 4) = r1;
}

// ---------------------------------------------------------------------------
extern "C" void kernel_launch(void* const* d_in, const int* in_sizes, int n_in,
                              void* d_out, int out_size, void* d_ws, size_t ws_size,
                              hipStream_t stream)
{
  const float* feats  = (const float*)d_in[0];   // [128,36,1024]
  const float* centre = (const float*)d_in[1];   // [128,36,2]
  const int*   nbr    = (const int*)  d_in[2];   // [4608,16]
  const float* gw     = (const float*)d_in[3];   // [73728,1]
  const float* mrho   = (const float*)d_in[4];
  const float* mth    = (const float*)d_in[5];
  const float* prho   = (const float*)d_in[6];
  const float* pth    = (const float*)d_in[7];
  const float* cw     = (const float*)d_in[8];   // [8,128,1024] == [1024,1024]
  float* out = (float*)d_out;

  // workspace layout (total ~13.9 MB)
  char* ws = (char*)d_ws;
  unsigned short* wb   = (unsigned short*)(ws);              //  2,097,152 B
  unsigned short* proj = (unsigned short*)(ws + 2097152);    //  9,437,184 B
  float*          ewg  = (float*)         (ws + 11534336);   //  2,359,296 B

  const int NW4 = (C_DIM * OUTD) / 4;
  const int EWB = (E_EDGES + 255) / 256;                     // 288 blocks
  castw_ew_kernel<<<dim3(NW4 / 256 + EWB), dim3(256), 0, stream>>>(
      cw, centre, nbr, gw, mrho, mth, prho, pth, wb, ewg);
  // CALIBRATION: 5 identical idempotent GEMM launches; delta vs R2's
  // 121.64 us = 4 x (GEMM dur + launch gap).
  for (int rep = 0; rep < 5; ++rep)
    gemm_fused<<<dim3(BN_NODES / TM, OUTD / TN), dim3(256), 0, stream>>>(
        feats, wb, proj);
  agg_gather<<<dim3(BN_NODES / 2), dim3(256), 0, stream>>>(proj, nbr, ewg, out);
}

// Round 6
// 120.319 us; speedup vs baseline: 1.6803x; 1.6803x over previous
//
#include <hip/hip_runtime.h>
#include <hip/hip_bf16.h>
#include <stdint.h>

// Problem constants (fixed by the reference)
#define B_DIM   128
#define N_DIM   36
#define C_DIM   1024
#define KNB     16
#define NKER    8
#define OUTD    1024
#define BN_NODES (B_DIM * N_DIM)     // 4608
#define E_EDGES  (BN_NODES * KNB)    // 73728
#define PI_F 3.14159265358979323846f

// R6: R2 structure (best measured; R5 calibration: GEMM+gap = 20.1 us) with
// ONE change: counted-vmcnt barrier (T4). R2's __syncthreads drained
// vmcnt(0) ~200cyc after issuing DMAB(t+1) -> ~300cyc stall/iter. Now the
// barrier waits vmcnt(7): the 7 newest ops (LOADA(t+1) 3 + DMAB(t+1) 4)
// stay in flight across the barrier; only DMAB(t) is retired. Cover for a
// B-tile's DMA grows to a full iteration.
#define TM 48
#define TN 128
#define BK 64
#define KIT (C_DIM / BK)   // 16
#define CLP 136            // epilogue C-tile LDS leading dim
// LDS shorts: A bufs 2*48*64 = 6144, B bufs 2*128*64 = 16384 -> 22528 (45 KB)
#define A_OFF(p) ((p) * TM * BK)                 // 0 / 3072
#define B_OFF(p) (2 * TM * BK + (p) * TN * BK)   // 6144 / 14336

typedef __attribute__((ext_vector_type(8))) short bf16x8;   // 8 bf16 = 4 VGPRs
typedef __attribute__((ext_vector_type(4))) float floatx4;  // MFMA C/D frag

struct alignas(8)  U16x4 { unsigned short x, y, z, w; };
struct alignas(16) U16x8 { unsigned short s[8]; };

__device__ __forceinline__ unsigned short f2bf(float f) {
  union { float f; uint32_t u; } v; v.f = f;
  uint32_t u = v.u;
  return (unsigned short)((u + 0x7fffu + ((u >> 16) & 1u)) >> 16);  // RNE
}
__device__ __forceinline__ float bf2f_lo(uint32_t pair) {
  union { uint32_t u; float f; } v; v.u = pair << 16;
  return v.f;
}
__device__ __forceinline__ float bf2f_hi(uint32_t pair) {
  union { uint32_t u; float f; } v; v.u = pair & 0xffff0000u;
  return v.f;
}

// async global -> LDS, 16B per lane (global_load_lds_dwordx4).
__device__ __forceinline__ void gload16(const void* g, void* l) {
  __builtin_amdgcn_global_load_lds((__attribute__((address_space(1))) void*)(g),
                                   (__attribute__((address_space(3))) void*)(l),
                                   16, 0, 0);
}

// ---------------------------------------------------------------------------
// Kernel 1: cast conv_w fp32->bf16 + precompute normalized edge weights.
// ---------------------------------------------------------------------------
__global__ __launch_bounds__(256)
void castw_ew_kernel(const float* __restrict__ cw,       // [1024*1024]
                     const float* __restrict__ centre,   // [BN][2]
                     const int*   __restrict__ nbr,      // [BN][16]
                     const float* __restrict__ gw,       // [E]
                     const float* __restrict__ mrho,
                     const float* __restrict__ mth,
                     const float* __restrict__ prho,
                     const float* __restrict__ pth,
                     unsigned short* __restrict__ wb,
                     float* __restrict__ ewg)            // [BN][NKER][KNB]
{
  const int NW4 = (C_DIM * OUTD) / 4;       // 262144
  int tid = blockIdx.x * 256 + threadIdx.x;
  if (tid < NW4) {
    float4 v = ((const float4*)cw)[tid];
    U16x4 o = { f2bf(v.x), f2bf(v.y), f2bf(v.z), f2bf(v.w) };
    ((U16x4*)wb)[tid] = o;
  } else {
    int e = tid - NW4;
    if (e < E_EDGES) {
      int n = e >> 4;
      int m = nbr[e];
      float cx = centre[2 * n]     - centre[2 * m];
      float cy = centre[2 * n + 1] - centre[2 * m + 1];
      float rho   = sqrtf(cx * cx + cy * cy);
      float theta = atan2f(cx, cy);      // jnp.arctan2(coord_x, coord_y)
      float wk[NKER];
      float s = 0.f;
#pragma unroll
      for (int k = 0; k < NKER; ++k) {
        float dr = rho - mrho[k];
        float pr = prho[k];
        float w_r = expf(-0.5f * dr * dr / (1e-14f + pr * pr));
        float fa = fabsf(theta - mth[k]);
        float sa = fabsf(2.0f * PI_F - fa);
        float mm = fminf(fa, sa);
        float pt = pth[k];
        float w_t = expf(-0.5f * mm * mm / (1e-14f + pt * pt));
        float ww = w_r * w_t;
        wk[k] = (ww != ww) ? 0.f : ww;   // NaN guard (reference parity)
        s += wk[k];
      }
      float scale = gw[e] / s;
      int j = e & 15;
#pragma unroll
      for (int k = 0; k < NKER; ++k)
        ewg[(size_t)n * (NKER * KNB) + k * KNB + j] = wk[k] * scale;
    }
  }
}

// ---------------------------------------------------------------------------
// Kernel 2: proj = feats(fp32, cast in-kernel) @ conv_w^T(bf16, gload_lds).
// R2 structure: 48x128 tile, 4 waves as 1x4 (48x32 each), dbuf BK=64.
// R6: counted-vmcnt barrier replaces __syncthreads (see header comment).
// Race structure identical to R2: between consecutive barriers a wave only
// reads buf p and writes buf 1-p (disjoint); one barrier per iter.
// ---------------------------------------------------------------------------
__global__ __launch_bounds__(256)
void gemm_fused(const float* __restrict__ A,            // [4608][1024] fp32
                const unsigned short* __restrict__ Bt,  // [1024][1024] bf16
                unsigned short* __restrict__ D)         // [4608][1024] bf16
{
  __shared__ unsigned short smem[2 * TM * BK + 2 * TN * BK];  // 45 KB

  const int tid  = threadIdx.x;
  const int lane = tid & 63;
  const int wv   = tid >> 6;        // wave 0..3 -> col group of 32
  const int row0 = blockIdx.x * TM;
  const int col0 = blockIdx.y * TN;

  const int q  = lane >> 4;         // quad
  const int lr = lane & 15;

  floatx4 acc[3][2] = {};

  // ---- B staging map (16B chunks, chunk c -> row c>>3, qcol c&7, XOR) ----
  int offB[4];
#pragma unroll
  for (int i = 0; i < 4; ++i) {
    int c = tid + 256 * i, row = c >> 3, qc = c & 7;
    offB[i] = (col0 + row) * C_DIM + (qc ^ (row & 7)) * 8;
  }

  // ---- A staging map (fp32 source -> bf16 LDS, XOR swizzle) ----
  const int r0A = tid >> 3;                      // rows 0..31
  const int gA0 = (row0 + r0A) * C_DIM + (tid & 7) * 8;
  const int r2A = 32 + (tid >> 4);               // rows 32..47
  const int gA2 = (row0 + r2A) * C_DIM + (tid & 15) * 4;
  const int wA0 = r0A * BK + (((tid & 7) ^ (r0A & 7)) * 8);
  const int wA2 = r2A * BK + ((((tid >> 1) & 7) ^ (r2A & 7)) * 8) + (tid & 1) * 4;

  float4 a0, a1, a2;

#define LOADA(T) do {                                                        \
    a0 = *(const float4*)&A[gA0 + (T) * BK];                                 \
    a1 = *(const float4*)&A[gA0 + 4 + (T) * BK];                             \
    a2 = *(const float4*)&A[gA2 + (T) * BK];                                 \
  } while (0)

#define WRITEA(P) do {                                                       \
    U16x8 w8;                                                                \
    w8.s[0] = f2bf(a0.x); w8.s[1] = f2bf(a0.y);                              \
    w8.s[2] = f2bf(a0.z); w8.s[3] = f2bf(a0.w);                              \
    w8.s[4] = f2bf(a1.x); w8.s[5] = f2bf(a1.y);                              \
    w8.s[6] = f2bf(a1.z); w8.s[7] = f2bf(a1.w);                              \
    *(U16x8*)&smem[A_OFF(P) + wA0] = w8;                                     \
    U16x4 w4 = { f2bf(a2.x), f2bf(a2.y), f2bf(a2.z), f2bf(a2.w) };           \
    *(U16x4*)&smem[A_OFF(P) + wA2] = w4;                                     \
  } while (0)

#define DMAB(T, P) do {                                                      \
    _Pragma("unroll") for (int i = 0; i < 4; ++i)                            \
      gload16(Bt + offB[i] + (T) * BK,                                       \
              &smem[B_OFF(P) + (tid + 256 * i) * 8]);                        \
  } while (0)

  // prologue: tile 0 into buf 0 (issue order: A loads first, then B DMA,
  // so WRITEA's a-reg dependency waits vmcnt(4), leaving DMAB in flight)
  LOADA(0);
  __builtin_amdgcn_sched_barrier(0);
  DMAB(0, 0);
  WRITEA(0);            // compiler-inserted vmcnt(4) for a0..a2

  for (int t = 0; t < KIT; ++t) {
    const int p = t & 1;
    if (t + 1 < KIT) {
      LOADA(t + 1);                        // 3 loads (oldest of the new 7)
      __builtin_amdgcn_sched_barrier(0);   // pin order: A-loads before B-DMA
      DMAB(t + 1, 1 - p);                  // 4 gload_lds
      // Retire DMAB(t) (older than the 7 just issued); keep t+1's 7 ops in
      // flight across the barrier. lgkmcnt(0): WRITEA(p) ds_writes visible.
      asm volatile("s_waitcnt vmcnt(7) lgkmcnt(0)\n\ts_barrier" ::: "memory");
    } else {
      asm volatile("s_waitcnt vmcnt(0) lgkmcnt(0)\n\ts_barrier" ::: "memory");
    }

    const int aBase = A_OFF(p);
    const int bBase = B_OFF(p);
#pragma unroll
    for (int kc = 0; kc < 2; ++kc) {
      const int sc = ((kc * 4 + q) ^ (lr & 7)) * 8;
      bf16x8 af[3], bfr[2];
#pragma unroll
      for (int i = 0; i < 3; ++i)
        af[i]  = *(const bf16x8*)&smem[aBase + (i * 16 + lr) * BK + sc];
#pragma unroll
      for (int j = 0; j < 2; ++j)
        bfr[j] = *(const bf16x8*)&smem[bBase + (wv * 32 + j * 16 + lr) * BK + sc];
#pragma unroll
      for (int i = 0; i < 3; ++i)
#pragma unroll
        for (int j = 0; j < 2; ++j)
          acc[i][j] = __builtin_amdgcn_mfma_f32_16x16x32_bf16(
              af[i], bfr[j], acc[i][j], 0, 0, 0);
    }

    if (t + 1 < KIT) WRITEA(1 - p);  // compiler vmcnt(4): waits A-loads only
  }
#undef LOADA
#undef WRITEA
#undef DMAB

  // rotation removed the end-of-loop barrier; epilogue reuses smem -> sync
  __syncthreads();

  // ---- epilogue: stage C tile (48x128 bf16) in LDS, coalesced stores ----
#pragma unroll
  for (int i = 0; i < 3; ++i)
#pragma unroll
    for (int j = 0; j < 2; ++j)
#pragma unroll
      for (int r = 0; r < 4; ++r)
        smem[(i * 16 + q * 4 + r) * CLP + wv * 32 + j * 16 + lr] =
            f2bf(acc[i][j][r]);
  __syncthreads();
  // full tile = 48 rows x 16 chunks = 768 chunks; thread t does 3
#pragma unroll
  for (int i = 0; i < 3; ++i) {
    int c = tid + 256 * i;
    int row = c >> 4, qc = c & 15;
    *(uint4*)&D[(size_t)(row0 + row) * OUTD + col0 + qc * 8] =
        *(const uint4*)&smem[row * CLP + qc * 8];
  }
}

// ---------------------------------------------------------------------------
// Kernel 3: pure gather-aggregate, channel-sliced + XCD-pinned (unchanged).
// ---------------------------------------------------------------------------
__global__ __launch_bounds__(256)
void agg_gather(const unsigned short* __restrict__ proj,  // [BN][1024] bf16
                const int*   __restrict__ nbr,            // [BN][16]
                const float* __restrict__ ewg,            // [BN][NKER][KNB]
                float* __restrict__ out)                  // [BN][1024] fp32
{
  __shared__ int   idx[8][KNB];
  __shared__ float ewl[8][2][KNB];

  const int bid = blockIdx.x;
  const int x   = bid & 7;                    // XCD (round-robin dispatch)
  const int s   = x >> 1;                     // channel slice 0..3
  const int g   = ((bid >> 3) << 1) | (x & 1);// node group 0..575
  const int n0  = g * 8;
  const int t   = threadIdx.x;

  if (t < 128)
    idx[t >> 4][t & 15] = nbr[(n0 + (t >> 4)) * KNB + (t & 15)];
  {
    int a = t >> 5, r = t & 31;
    ewl[a][r >> 4][r & 15] = ewg[(size_t)(n0 + a) * (NKER * KNB) + s * 32 + r];
  }
  __syncthreads();

  const int a   = t >> 5;
  const int cu  = t & 31;
  const int kk  = cu >> 4;
  const int n   = n0 + a;
  const int ch0 = s * 256 + cu * 8;

  float acc[8] = {0.f, 0.f, 0.f, 0.f, 0.f, 0.f, 0.f, 0.f};
#pragma unroll
  for (int j = 0; j < KNB; ++j) {
    float wvv = ewl[a][kk][j];
    uint4 v = *(const uint4*)&proj[(size_t)idx[a][j] * OUTD + ch0];
    acc[0] += wvv * bf2f_lo(v.x);  acc[1] += wvv * bf2f_hi(v.x);
    acc[2] += wvv * bf2f_lo(v.y);  acc[3] += wvv * bf2f_hi(v.y);
    acc[4] += wvv * bf2f_lo(v.z);  acc[5] += wvv * bf2f_hi(v.z);
    acc[6] += wvv * bf2f_lo(v.w);  acc[7] += wvv * bf2f_hi(v.w);
  }
  float4 r0, r1;
  r0.x = fmaxf(acc[0], 0.f); r0.y = fmaxf(acc[1], 0.f);
  r0.z = fmaxf(acc[2], 0.f); r0.w = fmaxf(acc[3], 0.f);
  r1.x = fmaxf(acc[4], 0.f); r1.y = fmaxf(acc[5], 0.f);
  r1.z = fmaxf(acc[6], 0.f); r1.w = fmaxf(acc[7], 0.f);
  float* o = out + (size_t)n * OUTD + ch0;
  *(float4*)(o)     = r0;
  *(float4*)(o + 4) = r1;
}

// ---------------------------------------------------------------------------
extern "C" void kernel_launch(void* const* d_in, const int* in_sizes, int n_in,
                              void* d_out, int out_size, void* d_ws, size_t ws_size,
                              hipStream_t stream)
{
  const float* feats  = (const float*)d_in[0];   // [128,36,1024]
  const float* centre = (const float*)d_in[1];   // [128,36,2]
  const int*   nbr    = (const int*)  d_in[2];   // [4608,16]
  const float* gw     = (const float*)d_in[3];   // [73728,1]
  const float* mrho   = (const float*)d_in[4];
  const float* mth    = (const float*)d_in[5];
  const float* prho   = (const float*)d_in[6];
  const float* pth    = (const float*)d_in[7];
  const float* cw     = (const float*)d_in[8];   // [8,128,1024] == [1024,1024]
  float* out = (float*)d_out;

  // workspace layout (total ~13.9 MB)
  char* ws = (char*)d_ws;
  unsigned short* wb   = (unsigned short*)(ws);              //  2,097,152 B
  unsigned short* proj = (unsigned short*)(ws + 2097152);    //  9,437,184 B
  float*          ewg  = (float*)         (ws + 11534336);   //  2,359,296 B

  const int NW4 = (C_DIM * OUTD) / 4;
  const int EWB = (E_EDGES + 255) / 256;                     // 288 blocks
  castw_ew_kernel<<<dim3(NW4 / 256 + EWB), dim3(256), 0, stream>>>(
      cw, centre, nbr, gw, mrho, mth, prho, pth, wb, ewg);
  gemm_fused<<<dim3(BN_NODES / TM, OUTD / TN), dim3(256), 0, stream>>>(
      feats, wb, proj);
  agg_gather<<<dim3(BN_NODES / 2), dim3(256), 0, stream>>>(proj, nbr, ewg, out);
}